// Round 1
// baseline (300.852 us; speedup 1.0000x reference)
//
#include <hip/hip_runtime.h>
#include <hip/hip_bf16.h>
#include <cstdint>
#include <cstddef>

// Problem constants (B=4, S=4096, D=1024, DFF=4096, K_ACT=1024)
#define Bz 4
#define Sz 4096
#define Dz 1024
#define DFFz 4096
#define KACT 1024

typedef __bf16 bf16;
typedef __attribute__((ext_vector_type(8))) __bf16 bf16x8;
typedef __attribute__((ext_vector_type(4))) __bf16 bf16x4;
typedef __attribute__((ext_vector_type(4))) float f32x4;

__device__ __forceinline__ void async16(const void* g, void* l) {
  __builtin_amdgcn_global_load_lds(
      (const __attribute__((address_space(1))) void*)g,
      (__attribute__((address_space(3))) void*)l, 16, 0, 0);
}

// ---- fused prep: [0,4096) router+zero | [4096,8192) w1 transpose | [8192,12288) w2 transpose ----
__global__ __launch_bounds__(256) void prep_k(const float* __restrict__ x,
                                              const float* __restrict__ rw,
                                              const float* __restrict__ rb,
                                              float* __restrict__ scores,
                                              float4* __restrict__ out4,
                                              const float* __restrict__ w1,
                                              bf16* __restrict__ w1T,
                                              const float* __restrict__ w2,
                                              bf16* __restrict__ w2T) {
  __shared__ float t[32][33];
  const int bid = blockIdx.x;
  const int tid = threadIdx.x;
  if (bid < 4096) {
    int row = bid * 4 + (tid >> 6);
    int lane = tid & 63;
    const float4* xr = (const float4*)(x + (size_t)row * Dz);
    const float4* wr = (const float4*)rw;
    float acc = 0.f;
#pragma unroll
    for (int i = 0; i < 4; ++i) {
      float4 a = xr[lane + i * 64];
      float4 w = wr[lane + i * 64];
      acc += a.x * w.x + a.y * w.y + a.z * w.z + a.w * w.w;
    }
#pragma unroll
    for (int d = 32; d; d >>= 1) acc += __shfl_down(acc, d, 64);
    if (lane == 0) scores[row] = acc + rb[0];
    float4* o = out4 + (size_t)bid * 4 * (Dz / 4);
    const float4 z = make_float4(0.f, 0.f, 0.f, 0.f);
#pragma unroll
    for (int i = 0; i < 4; ++i) o[tid + i * 256] = z;
  } else {
    const float* in; bf16* outp; int R, C, bx, by;
    if (bid < 8192) {
      in = w1; outp = w1T; R = Dz; C = DFFz;
      bx = (bid - 4096) & 127; by = (bid - 4096) >> 7;   // (128, 32)
    } else {
      in = w2; outp = w2T; R = DFFz; C = Dz;
      bx = (bid - 8192) & 31; by = (bid - 8192) >> 5;    // (32, 128)
    }
    int c0 = bx * 32, r0 = by * 32;
    int tx = tid & 31, ty = tid >> 5;  // (32, 8)
#pragma unroll
    for (int i = 0; i < 32; i += 8) t[ty + i][tx] = in[(size_t)(r0 + ty + i) * C + c0 + tx];
    __syncthreads();
#pragma unroll
    for (int i = 0; i < 32; i += 8)
      outp[(size_t)(c0 + ty + i) * R + r0 + tx] = (bf16)t[tx][ty + i];
  }
}

// ---- select top-K per batch, 16 tokens/block: scores staged in LDS once ----
__global__ __launch_bounds__(256) void select_gather_k(
    const float* __restrict__ x, const float* __restrict__ scores,
    int* __restrict__ sel_idx, float* __restrict__ gates, bf16* __restrict__ Xsel) {
  int b = blockIdx.x >> 8;            // 256 blocks per batch row
  int s0 = (blockIdx.x & 255) * 16;   // first of 16 tokens
  __shared__ float sc[Sz];
  __shared__ int red[16][4];
  __shared__ int rk[16];
  const int tid = threadIdx.x;
  const int wave = tid >> 6, lane = tid & 63;
  const float* srow = scores + (size_t)b * Sz;
#pragma unroll
  for (int i = 0; i < 4; ++i)
    ((float4*)sc)[tid + i * 256] = ((const float4*)srow)[tid + i * 256];
  __syncthreads();
  float mine[16];
#pragma unroll
  for (int j = 0; j < 16; ++j) mine[j] = sc[s0 + j];
  int cnt[16] = {};
  for (int t = tid; t < Sz; t += 256) {
    float o = sc[t];
#pragma unroll
    for (int j = 0; j < 16; ++j)
      cnt[j] += (o > mine[j]) || (o == mine[j] && t < s0 + j);
  }
#pragma unroll
  for (int j = 0; j < 16; ++j) {
    int c = cnt[j];
#pragma unroll
    for (int d = 32; d; d >>= 1) c += __shfl_down(c, d, 64);
    if (lane == 0) red[j][wave] = c;
  }
  __syncthreads();
  if (tid < 16) {
    int rank = red[tid][0] + red[tid][1] + red[tid][2] + red[tid][3];
    rk[tid] = rank;
    if (rank < KACT) {
      int m = b * KACT + rank;
      sel_idx[m] = s0 + tid;
      gates[m] = 1.f / (1.f + expf(-sc[s0 + tid]));
    }
  }
  __syncthreads();
#pragma unroll
  for (int j = 0; j < 16; ++j) {
    int rank = rk[j];
    if (rank >= KACT) continue;
    int m = b * KACT + rank;
    float4 v = ((const float4*)(x + ((size_t)b * Sz + s0 + j) * Dz))[tid];
    bf16x4 o = {(bf16)v.x, (bf16)v.y, (bf16)v.z, (bf16)v.w};
    ((bf16x4*)(Xsel + (size_t)m * Dz))[tid] = o;
  }
}

// ======== m97-structure GEMM: 256 threads / 4 waves, 128x128 tile, BK=32,
// single-buffer 16 KB LDS, 2 barriers per K-step. ALL waves stage via
// global_load_lds width-16 AND compute (4x4 acc of 16x16x32 per wave).
// Latency hiding comes from 3-4 resident blocks/CU (m114), not intra-block
// producer/consumer split (which halved MFMA issue capacity: 335 TF -> target ~870).
#define STAGE128(k0)                                                           \
  {                                                                            \
    async16(Ag + (k0), &As[tid * 8]);                                          \
    async16(Ag + (size_t)64 * K + (k0), &As[2048 + tid * 8]);                  \
    async16(Bg + (k0), &Bs[tid * 8]);                                          \
    async16(Bg + (size_t)64 * K + (k0), &Bs[2048 + tid * 8]);                  \
  }

#define GEMM128_BODY(KV, KOFF, NITER)                                          \
  __shared__ __align__(16) bf16 As[128 * 32]; /* 8 KB */                       \
  __shared__ __align__(16) bf16 Bs[128 * 32]; /* 8 KB */                       \
  constexpr int K = (KV);                                                      \
  const int tid = threadIdx.x;                                                 \
  const int wave = tid >> 6, lane = tid & 63;                                  \
  const int quad = lane >> 4, l16 = lane & 15;                                 \
  const int m0 = blockIdx.y * 128, n0 = blockIdx.x * 128;                      \
  const int wm = (wave >> 1) * 64, wn = (wave & 1) * 64;                       \
  /* staging map: thread t -> chunk t (rows 0-63) and t+256 (rows 64-127); */  \
  /* chunk c = row*4 + colq, LDS dest = linear c*16B (wave-uniform+lane*16) */ \
  const bf16* Ag = A + (size_t)(m0 + (tid >> 2)) * K + (KOFF) + (tid & 3) * 8; \
  const bf16* Bg = Bt + (size_t)(n0 + (tid >> 2)) * K + (KOFF) + (tid & 3) * 8;\
  f32x4 acc[4][4] = {};                                                        \
  STAGE128(0)                                                                  \
  for (int it = 0; it < (NITER); ++it) {                                       \
    __syncthreads(); /* drains vmcnt(0): staged tile visible */                \
    bf16x8 af[4], bfr[4];                                                      \
    _Pragma("unroll")                                                          \
    for (int i = 0; i < 4; ++i) {                                              \
      af[i] = *(const bf16x8*)&As[(wm + i * 16 + l16) * 32 + quad * 8];        \
      bfr[i] = *(const bf16x8*)&Bs[(wn + i * 16 + l16) * 32 + quad * 8];       \
    }                                                                          \
    _Pragma("unroll")                                                          \
    for (int mi = 0; mi < 4; ++mi)                                             \
      _Pragma("unroll")                                                        \
      for (int ni = 0; ni < 4; ++ni)                                           \
        acc[mi][ni] = __builtin_amdgcn_mfma_f32_16x16x32_bf16(af[mi], bfr[ni], acc[mi][ni], 0, 0, 0); \
    __syncthreads(); /* all waves done reading before overwrite */             \
    if (it + 1 < (NITER)) { STAGE128((it + 1) * 32) }                          \
  }

// ---------------- GEMM1: H = gelu(Xsel @ w1 + b1), M=4096 N=4096 K=1024 ----------------
__global__ __launch_bounds__(256) void gemm1_k(const bf16* __restrict__ A,
                                               const bf16* __restrict__ Bt,
                                               const float* __restrict__ bias,
                                               bf16* __restrict__ H) {
  GEMM128_BODY(Dz, 0, Dz / 32)
  // epilogue: bias + exact GELU -> bf16   (C/D layout: col=lane&15, row=quad*4+reg)
#pragma unroll
  for (int mi = 0; mi < 4; ++mi) {
    int mbase = m0 + wm + mi * 16 + quad * 4;
#pragma unroll
    for (int ni = 0; ni < 4; ++ni) {
      int n = n0 + wn + ni * 16 + l16;
      float bn = bias[n];
#pragma unroll
      for (int r = 0; r < 4; ++r) {
        float z = acc[mi][ni][r] + bn;
        float g = 0.5f * z * (1.f + erff(z * 0.70710678118654752f));
        H[(size_t)(mbase + r) * DFFz + n] = (bf16)g;
      }
    }
  }
}

// ---- GEMM2 main, split-K=2 non-atomic: P[c] = (H @ w2)_chunk as bf16 partials ----
// M=4096 N=1024 K=4096 -> 2 chunks of 2048; grid 8x32x2 = 512 blocks (2/CU overlap).
__global__ __launch_bounds__(256) void gemm2_k(const bf16* __restrict__ A,
                                               const bf16* __restrict__ Bt,
                                               bf16* __restrict__ P) {
  GEMM128_BODY(DFFz, blockIdx.z * 2048, 2048 / 32)
  bf16* Pc = P + (size_t)blockIdx.z * Bz * KACT * Dz;
#pragma unroll
  for (int mi = 0; mi < 4; ++mi) {
    int mbase = m0 + wm + mi * 16 + quad * 4;
#pragma unroll
    for (int ni = 0; ni < 4; ++ni) {
      int n = n0 + wn + ni * 16 + l16;
#pragma unroll
      for (int r = 0; r < 4; ++r)
        Pc[(size_t)(mbase + r) * Dz + n] = (bf16)acc[mi][ni][r];
    }
  }
}

// ---- reduce partials + bias + gate + scatter: out[b,sel[m],:] = (P0+P1+b2)*gate ----
__global__ __launch_bounds__(256) void reduce_k(const bf16* __restrict__ P,
                                                const float* __restrict__ bias,
                                                const int* __restrict__ sel_idx,
                                                const float* __restrict__ gates,
                                                float* __restrict__ out) {
  int m = blockIdx.x;
  int b = m >> 10;
  int s = sel_idx[m];
  float gt = gates[m];
  int tid = threadIdx.x;
  const bf16x4* p0 = (const bf16x4*)(P + (size_t)m * Dz);
  const bf16x4* p1 = (const bf16x4*)(P + (size_t)Bz * KACT * Dz + (size_t)m * Dz);
  const float4* bv = (const float4*)bias;
  float4* orow = (float4*)(out + ((size_t)b * Sz + s) * Dz);
  bf16x4 a = p0[tid], c = p1[tid];
  float4 bb = bv[tid];
  float4 o;
  o.x = ((float)a[0] + (float)c[0] + bb.x) * gt;
  o.y = ((float)a[1] + (float)c[1] + bb.y) * gt;
  o.z = ((float)a[2] + (float)c[2] + bb.z) * gt;
  o.w = ((float)a[3] + (float)c[3] + bb.w) * gt;
  orow[tid] = o;
}

extern "C" void kernel_launch(void* const* d_in, const int* in_sizes, int n_in,
                              void* d_out, int out_size, void* d_ws, size_t ws_size,
                              hipStream_t stream) {
  (void)in_sizes; (void)n_in; (void)out_size; (void)ws_size;
  const float* x  = (const float*)d_in[0];
  const float* rw = (const float*)d_in[1];
  const float* rb = (const float*)d_in[2];
  const float* w1 = (const float*)d_in[3];
  const float* b1 = (const float*)d_in[4];
  const float* w2 = (const float*)d_in[5];
  const float* b2 = (const float*)d_in[6];
  float* out = (float*)d_out;

  char* ws = (char*)d_ws;
  float* scores = (float*)ws;  ws += (size_t)Bz * Sz * 4;          // 64 KB
  int*   sel_idx = (int*)ws;   ws += (size_t)Bz * KACT * 4;        // 16 KB
  float* gates = (float*)ws;   ws += (size_t)Bz * KACT * 4;        // 16 KB
  bf16*  w2T = (bf16*)ws;      ws += (size_t)Dz * DFFz * 2;        // 8 MB  [1024][4096]
  bf16*  H = (bf16*)ws;        ws += (size_t)Bz * KACT * DFFz * 2; // 32 MB [4096][4096]
  bf16*  w1T = (bf16*)ws;      ws += (size_t)DFFz * Dz * 2;        // 8 MB  [4096][1024]
  bf16*  Xsel = (bf16*)ws;     ws += (size_t)Bz * KACT * Dz * 2;   // 8 MB  [4096][1024]
  // P (2 x 8 MB bf16 partials) overlays w1T+Xsel, both dead after gemm1.
  bf16*  P = w1T;

  prep_k<<<3 * 4096, 256, 0, stream>>>(x, rw, rb, scores, (float4*)out, w1, w1T, w2, w2T);
  select_gather_k<<<Bz * (Sz / 16), 256, 0, stream>>>(x, scores, sel_idx, gates, Xsel);
  gemm1_k<<<dim3(DFFz / 128, (Bz * KACT) / 128), 256, 0, stream>>>(Xsel, w1T, b1, H);
  gemm2_k<<<dim3(Dz / 128, (Bz * KACT) / 128, 2), 256, 0, stream>>>(H, w2T, P);
  reduce_k<<<Bz * KACT, 256, 0, stream>>>(P, b2, sel_idx, gates, out);
}